// Round 4
// baseline (448.480 us; speedup 1.0000x reference)
//
#include <hip/hip_runtime.h>

constexpr int BB = 2, HH = 16, LL = 2048, DD = 128;
constexpr int QB = 64, KB = 32, NKT = LL / KB;
constexpr float SCALE = 0.08838834764831845f;  // 1/sqrt(128)

typedef __attribute__((ext_vector_type(8))) short bf16x8;
typedef __attribute__((ext_vector_type(8))) unsigned short u16x8;
typedef __attribute__((ext_vector_type(4))) float f32x4;

static __device__ __forceinline__ unsigned short f2bf(float f) {
  unsigned int u = __builtin_bit_cast(unsigned int, f);
  u += 0x7fffu + ((u >> 16) & 1u);   // RNE
  return (unsigned short)(u >> 16);
}
static __device__ __forceinline__ int slotRC(int r) { return ((r >> 1) ^ (r >> 3)) & 3; }

#define GLD16(gsrc, ldst) __builtin_amdgcn_global_load_lds( \
    (const __attribute__((address_space(1))) void*)(gsrc), \
    (__attribute__((address_space(3))) void*)(ldst), 16, 0, 0)

#define CFENCE asm volatile("" ::: "memory")
#define WAITVM0 asm volatile("s_waitcnt vmcnt(0)" ::: "memory")
#define WAITVM4 asm volatile("s_waitcnt vmcnt(4)" ::: "memory")
#define WAITLGKM asm volatile("s_waitcnt lgkmcnt(0)" ::: "memory")
#define BARRIER __builtin_amdgcn_s_barrier()

// ---------- prep: K->bf16, V->bf16 transposed [bh][d][k], cpm = mask? probs*alpha : -1e30 ----------
__global__ __launch_bounds__(256)
void prep_kernel(const float* __restrict__ k, const float* __restrict__ v,
                 const int* __restrict__ mask, const float* __restrict__ probs,
                 const float* __restrict__ alphap,
                 unsigned short* __restrict__ kb, unsigned short* __restrict__ vt,
                 float* __restrict__ cpm)
{
  __shared__ unsigned short sT[128 * 72];   // padded transpose tile
  const int bid = blockIdx.x;
  const int bh = bid >> 5, kt = bid & 31;   // 64 keys per kt
  const int t = threadIdx.x;
  const float alpha = alphap[0];
  const float* kg = k + ((size_t)bh * LL + kt * 64) * DD;
  const float* vg = v + ((size_t)bh * LL + kt * 64) * DD;
  unsigned short* kbg = kb + ((size_t)bh * LL + kt * 64) * DD;
  #pragma unroll
  for (int i = 0; i < 8; ++i) {
    int idx = i * 256 + t;
    float4 x = ((const float4*)kg)[idx];
    ushort4 o; o.x = f2bf(x.x); o.y = f2bf(x.y); o.z = f2bf(x.z); o.w = f2bf(x.w);
    ((ushort4*)kbg)[idx] = o;
  }
  #pragma unroll
  for (int i = 0; i < 8; ++i) {
    int idx = i * 256 + t;
    int kr = idx >> 5;
    int d0 = (idx & 31) * 4;
    float4 x = ((const float4*)vg)[idx];
    sT[(d0 + 0) * 72 + kr] = f2bf(x.x);
    sT[(d0 + 1) * 72 + kr] = f2bf(x.y);
    sT[(d0 + 2) * 72 + kr] = f2bf(x.z);
    sT[(d0 + 3) * 72 + kr] = f2bf(x.w);
  }
  {
    const float4* ps = (const float4*)probs;
    const int4* ms = (const int4*)mask;
    float4* cs = (float4*)cpm;
    size_t base = (size_t)bid * 2048;
    #pragma unroll
    for (int i = 0; i < 8; ++i) {
      size_t idx = base + i * 256 + t;
      float4 p = ps[idx];
      int4 m = ms[idx];
      float4 o;
      o.x = m.x ? p.x * alpha : -1e30f;
      o.y = m.y ? p.y * alpha : -1e30f;
      o.z = m.z ? p.z * alpha : -1e30f;
      o.w = m.w ? p.w * alpha : -1e30f;
      cs[idx] = o;
    }
  }
  __syncthreads();
  const int d = t >> 1, h2 = t & 1;
  unsigned short* dst = vt + ((size_t)bh * DD + d) * LL + kt * 64 + h2 * 32;
  const unsigned short* srow = &sT[d * 72 + h2 * 32];
  *(u16x8*)(dst + 0)  = *(const u16x8*)(srow + 0);
  *(u16x8*)(dst + 8)  = *(const u16x8*)(srow + 8);
  *(u16x8*)(dst + 16) = *(const u16x8*)(srow + 16);
  *(u16x8*)(dst + 24) = *(const u16x8*)(srow + 24);
}

// ---------- main fused attention ----------
__global__ __launch_bounds__(512, 6)
void attn_kernel(const float* __restrict__ q, const unsigned short* __restrict__ kb,
                 const unsigned short* __restrict__ vt, const float* __restrict__ cpm,
                 float* __restrict__ outA, float* __restrict__ outP)
{
  __shared__ unsigned short sK[2][KB * DD];   // 16 KB dbuf (DMA-linear, src-swizzled)
  __shared__ unsigned short sVt[2][DD * KB];  // 16 KB dbuf (transposed V)
  __shared__ float sCP[2][QB * KB];           // 16 KB dbuf (probs*alpha+mask tile)
  __shared__ unsigned short sP[QB * KB];      // 4 KB (P tile; aliases sRed/sInv early)
  float* sRed = (float*)sP;
  float* sInv = ((float*)sP) + 128;

  const int tid = threadIdx.x;
  const int lane = tid & 63;
  const int wid = tid >> 6;
  const int l15 = lane & 15;
  const int l4 = lane >> 4;
  const int wr = wid >> 1, wc = wid & 1;

  const int bid = blockIdx.x;
  const int qt = bid >> 5;
  const int bh = bid & 31;     // consecutive WGs share cpm rows (L2/L3 reuse)
  const int b = bh >> 4;
  const int q0 = qt * QB;

  const float* qg = q + (size_t)(bh * LL + q0) * DD;
  const unsigned short* kbh = kb + (size_t)bh * LL * DD;
  const unsigned short* vbh = vt + (size_t)bh * DD * LL;
  const float* cg = cpm + (size_t)b * LL * LL + (size_t)q0 * LL;
  float* oA = outA + (size_t)(bh * LL + q0) * DD;
  float* oP = outP + (size_t)bh * LL * LL + (size_t)q0 * LL;

  // ---- Q -> LDS (staged in sK) -> registers ----
  unsigned short* sKf = &sK[0][0];
  {
    int row = tid >> 3;
    int d0 = (tid & 7) * 16;
    const float* src = qg + row * DD + d0;
    float4 x0 = *(const float4*)(src);
    float4 x1 = *(const float4*)(src + 4);
    float4 x2 = *(const float4*)(src + 8);
    float4 x3 = *(const float4*)(src + 12);
    u16x8 t0, t1;
    t0[0]=f2bf(x0.x); t0[1]=f2bf(x0.y); t0[2]=f2bf(x0.z); t0[3]=f2bf(x0.w);
    t0[4]=f2bf(x1.x); t0[5]=f2bf(x1.y); t0[6]=f2bf(x1.z); t0[7]=f2bf(x1.w);
    t1[0]=f2bf(x2.x); t1[1]=f2bf(x2.y); t1[2]=f2bf(x2.z); t1[3]=f2bf(x2.w);
    t1[4]=f2bf(x3.x); t1[5]=f2bf(x3.y); t1[6]=f2bf(x3.z); t1[7]=f2bf(x3.w);
    int sw = (row & 7) << 3;
    *(u16x8*)(&sKf[row * DD + (d0 ^ sw)]) = t0;
    *(u16x8*)(&sKf[row * DD + ((d0 + 8) ^ sw)]) = t1;
  }
  __syncthreads();
  const int qrow = wr * 16 + l15;
  const int qsw = (qrow & 7) << 3;
  bf16x8 qf0 = *(const bf16x8*)&sKf[qrow * DD + ((  0 + l4 * 8) ^ qsw)];
  bf16x8 qf1 = *(const bf16x8*)&sKf[qrow * DD + (( 32 + l4 * 8) ^ qsw)];
  bf16x8 qf2 = *(const bf16x8*)&sKf[qrow * DD + (( 64 + l4 * 8) ^ qsw)];
  bf16x8 qf3 = *(const bf16x8*)&sKf[qrow * DD + (( 96 + l4 * 8) ^ qsw)];
  __syncthreads();   // Q frags read; sK can be reused for K tiles

  // ---- DMA per-lane source offsets (source pre-swizzled, LDS linear) ----
  const int rK = (wid << 2) + (lane >> 4);                               // 0..31
  const size_t goffK = (size_t)rK * DD + (((lane & 15) ^ (rK & 7)) << 3);
  const int rV = (wid << 4) + (lane >> 2);                               // 0..127
  const size_t goffV = (size_t)rV * LL + (((lane & 3) ^ slotRC(rV)) << 3);
  const int rC = (wid << 3) + (lane >> 3);                               // 0..63
  const size_t goffC = (size_t)rC * LL + (((lane & 7) ^ (rC & 7)) << 2);
  const int ldsOff = wid << 9;   // 1 KB per wave (u16 elements)

  #define DMA_K(BUF, KT) GLD16(kbh + (size_t)(KT) * KB * DD + goffK, &sK[BUF][ldsOff])
  #define DMA_V(BUF, KT) GLD16(vbh + (size_t)(KT) * KB + goffV, &sVt[BUF][ldsOff])
  #define DMA_C(BUF, KT) GLD16(cg + (size_t)(KT) * KB + goffC, &sCP[BUF][wid << 8])

  const int keyloc = wc * 16 + l15;
  const int row0 = wr * 16 + l4 * 4;
  const int ksw = (keyloc & 7) << 3;
  // swizzle XOR uses (R&7): varies across the 4 l4-lane-groups -> <=2-way banks
  #define CPIDX(R, KEY) ((R) * 32 + (((((KEY) >> 2) ^ ((R) & 7)) << 2) | ((KEY) & 3)))

  // =================== PASS A: rowsums ===================
  float sum0 = 0.f, sum1 = 0.f, sum2 = 0.f, sum3 = 0.f;

  #define ABODY(KT) do { \
    const int cur = (KT) & 1; \
    f32x4 acc = {0.f, 0.f, 0.f, 0.f}; \
    bf16x8 bK; \
    bK = *(const bf16x8*)&sK[cur][keyloc * DD + ((  0 + l4 * 8) ^ ksw)]; \
    acc = __builtin_amdgcn_mfma_f32_16x16x32_bf16(qf0, bK, acc, 0, 0, 0); \
    bK = *(const bf16x8*)&sK[cur][keyloc * DD + (( 32 + l4 * 8) ^ ksw)]; \
    acc = __builtin_amdgcn_mfma_f32_16x16x32_bf16(qf1, bK, acc, 0, 0, 0); \
    bK = *(const bf16x8*)&sK[cur][keyloc * DD + (( 64 + l4 * 8) ^ ksw)]; \
    acc = __builtin_amdgcn_mfma_f32_16x16x32_bf16(qf2, bK, acc, 0, 0, 0); \
    bK = *(const bf16x8*)&sK[cur][keyloc * DD + (( 96 + l4 * 8) ^ ksw)]; \
    acc = __builtin_amdgcn_mfma_f32_16x16x32_bf16(qf3, bK, acc, 0, 0, 0); \
    sum0 += __expf(acc[0] * SCALE + sCP[cur][CPIDX(row0 + 0, keyloc)]); \
    sum1 += __expf(acc[1] * SCALE + sCP[cur][CPIDX(row0 + 1, keyloc)]); \
    sum2 += __expf(acc[2] * SCALE + sCP[cur][CPIDX(row0 + 2, keyloc)]); \
    sum3 += __expf(acc[3] * SCALE + sCP[cur][CPIDX(row0 + 3, keyloc)]); \
  } while (0)

  DMA_K(0, 0); DMA_C(0, 0);
  CFENCE;
  WAITVM0; BARRIER; CFENCE;
  DMA_K(1, 1); DMA_C(1, 1);
  CFENCE;
  ABODY(0);
  for (int kt = 1; kt < NKT; ++kt) {
    WAITVM0; BARRIER; CFENCE;           // tile kt resident; prev buffer free
    if (kt + 1 < NKT) { DMA_K((kt + 1) & 1, kt + 1); DMA_C((kt + 1) & 1, kt + 1); CFENCE; }
    ABODY(kt);
  }

  #pragma unroll
  for (int m = 1; m < 16; m <<= 1) {
    sum0 += __shfl_xor(sum0, m, 64);
    sum1 += __shfl_xor(sum1, m, 64);
    sum2 += __shfl_xor(sum2, m, 64);
    sum3 += __shfl_xor(sum3, m, 64);
  }
  __syncthreads();   // pass A fully done before sRed (sP alias) writes
  if (l15 == 0) {
    sRed[(row0 + 0) * 2 + wc] = sum0;
    sRed[(row0 + 1) * 2 + wc] = sum1;
    sRed[(row0 + 2) * 2 + wc] = sum2;
    sRed[(row0 + 3) * 2 + wc] = sum3;
  }
  __syncthreads();
  if (tid < QB) sInv[tid] = 1.0f / (sRed[tid * 2] + sRed[tid * 2 + 1]);
  __syncthreads();
  const float inv0 = sInv[row0 + 0], inv1 = sInv[row0 + 1],
              inv2 = sInv[row0 + 2], inv3 = sInv[row0 + 3];
  __syncthreads();   // everyone read sInv before sP overwrites it

  // =================== PASS B: attn_p + O ===================
  f32x4 o0 = {0,0,0,0}, o1 = {0,0,0,0}, o2 = {0,0,0,0}, o3 = {0,0,0,0};

  #define BBODY(KT) do { \
    const int cur = (KT) & 1; \
    f32x4 acc = {0.f, 0.f, 0.f, 0.f}; \
    bf16x8 bK; \
    bK = *(const bf16x8*)&sK[cur][keyloc * DD + ((  0 + l4 * 8) ^ ksw)]; \
    acc = __builtin_amdgcn_mfma_f32_16x16x32_bf16(qf0, bK, acc, 0, 0, 0); \
    bK = *(const bf16x8*)&sK[cur][keyloc * DD + (( 32 + l4 * 8) ^ ksw)]; \
    acc = __builtin_amdgcn_mfma_f32_16x16x32_bf16(qf1, bK, acc, 0, 0, 0); \
    bK = *(const bf16x8*)&sK[cur][keyloc * DD + (( 64 + l4 * 8) ^ ksw)]; \
    acc = __builtin_amdgcn_mfma_f32_16x16x32_bf16(qf2, bK, acc, 0, 0, 0); \
    bK = *(const bf16x8*)&sK[cur][keyloc * DD + (( 96 + l4 * 8) ^ ksw)]; \
    acc = __builtin_amdgcn_mfma_f32_16x16x32_bf16(qf3, bK, acc, 0, 0, 0); \
    const int keyg = (KT) * KB + keyloc; \
    float e0 = __expf(acc[0] * SCALE + sCP[cur][CPIDX(row0 + 0, keyloc)]) * inv0; \
    float e1 = __expf(acc[1] * SCALE + sCP[cur][CPIDX(row0 + 1, keyloc)]) * inv1; \
    float e2 = __expf(acc[2] * SCALE + sCP[cur][CPIDX(row0 + 2, keyloc)]) * inv2; \
    float e3 = __expf(acc[3] * SCALE + sCP[cur][CPIDX(row0 + 3, keyloc)]) * inv3; \
    oP[(size_t)(row0 + 0) * LL + keyg] = e0; \
    oP[(size_t)(row0 + 1) * LL + keyg] = e1; \
    oP[(size_t)(row0 + 2) * LL + keyg] = e2; \
    oP[(size_t)(row0 + 3) * LL + keyg] = e3; \
    sP[(row0 + 0) * KB + (keyloc ^ (slotRC(row0 + 0) << 3))] = f2bf(e0); \
    sP[(row0 + 1) * KB + (keyloc ^ (slotRC(row0 + 1) << 3))] = f2bf(e1); \
    sP[(row0 + 2) * KB + (keyloc ^ (slotRC(row0 + 2) << 3))] = f2bf(e2); \
    sP[(row0 + 3) * KB + (keyloc ^ (slotRC(row0 + 3) << 3))] = f2bf(e3); \
    WAITLGKM; BARRIER; CFENCE;   /* sP visible; NO vmcnt drain */ \
    bf16x8 aP = *(const bf16x8*)&sP[qrow * KB + ((l4 * 8) ^ (slotRC(qrow) << 3))]; \
    bf16x8 bV; \
    const int dc = wc * 64 + l15; \
    bV = *(const bf16x8*)&sVt[cur][(dc +  0) * KB + ((l4 * 8) ^ (slotRC(dc +  0) << 3))]; \
    o0 = __builtin_amdgcn_mfma_f32_16x16x32_bf16(aP, bV, o0, 0, 0, 0); \
    bV = *(const bf16x8*)&sVt[cur][(dc + 16) * KB + ((l4 * 8) ^ (slotRC(dc + 16) << 3))]; \
    o1 = __builtin_amdgcn_mfma_f32_16x16x32_bf16(aP, bV, o1, 0, 0, 0); \
    bV = *(const bf16x8*)&sVt[cur][(dc + 32) * KB + ((l4 * 8) ^ (slotRC(dc + 32) << 3))]; \
    o2 = __builtin_amdgcn_mfma_f32_16x16x32_bf16(aP, bV, o2, 0, 0, 0); \
    bV = *(const bf16x8*)&sVt[cur][(dc + 48) * KB + ((l4 * 8) ^ (slotRC(dc + 48) << 3))]; \
    o3 = __builtin_amdgcn_mfma_f32_16x16x32_bf16(aP, bV, o3, 0, 0, 0); \
  } while (0)

  DMA_K(0, 0); DMA_V(0, 0); DMA_C(0, 0);
  CFENCE;
  WAITVM0; BARRIER; CFENCE;
  DMA_K(1, 1); DMA_V(1, 1); DMA_C(1, 1);
  CFENCE;
  BBODY(0);
  for (int kt = 1; kt < NKT; ++kt) {
    // outstanding: [DMA(kt):3 loads, stores(kt-1):4] -> vmcnt(4) drains the
    // 3 loads (oldest) without waiting on this iteration's store retirement.
    WAITVM4; BARRIER; CFENCE;
    if (kt + 1 < NKT) {
      DMA_K((kt + 1) & 1, kt + 1); DMA_V((kt + 1) & 1, kt + 1); DMA_C((kt + 1) & 1, kt + 1);
      CFENCE;
    }
    BBODY(kt);
  }

  #pragma unroll
  for (int r = 0; r < 4; ++r) {
    float* dst = oA + (size_t)(row0 + r) * DD + wc * 64 + l15;
    dst[0]  = o0[r];
    dst[16] = o1[r];
    dst[32] = o2[r];
    dst[48] = o3[r];
  }
}

extern "C" void kernel_launch(void* const* d_in, const int* in_sizes, int n_in,
                              void* d_out, int out_size, void* d_ws, size_t ws_size,
                              hipStream_t stream) {
  const float* q = (const float*)d_in[0];
  const float* k = (const float*)d_in[1];
  const float* v = (const float*)d_in[2];
  const int* mask = (const int*)d_in[3];
  const float* probs = (const float*)d_in[4];
  const float* alpha = (const float*)d_in[5];
  float* outA = (float*)d_out;
  float* outP = outA + (size_t)BB * HH * LL * DD;
  unsigned short* kb16 = (unsigned short*)d_ws;
  unsigned short* vt16 = kb16 + (size_t)BB * HH * LL * DD;
  float* cpm = (float*)(vt16 + (size_t)BB * HH * LL * DD);
  hipLaunchKernelGGL(prep_kernel, dim3(BB * HH * 32), dim3(256), 0, stream,
                     k, v, mask, probs, alpha, kb16, vt16, cpm);
  hipLaunchKernelGGL(attn_kernel, dim3(BB * HH * (LL / QB)), dim3(512), 0, stream,
                     q, kb16, vt16, cpm, outA, outP);
}